// Round 6
// baseline (202.397 us; speedup 1.0000x reference)
//
#include <hip/hip_runtime.h>
#include <math.h>

#define Bb 2
#define Ss 128
#define Hh 768
#define Cc 5
#define Mm 256       // Bb*Ss
#define NEGV -1024.0f
#define SCALE 2.8853900817779268f   // 2/ln(2): stored pre-scaled so exp2(hp'+ha') = e^{2x}

// haT layout: [b][c][hg][a][hl], hg=h/4, hl=h&3
#define HA_B  491520   // 5*192*128*4
#define HA_C  98304    // 192*128*4
#define HA_HG 512      // 128*4

#define CHUNK_H 24
#define CHUNK_F 3072   // 24*128 floats = 12 KB
#define NCHUNK 32      // 768/24

typedef __attribute__((ext_vector_type(8))) short bf16x8;
typedef __attribute__((ext_vector_type(4))) float f32x4;

__device__ __forceinline__ unsigned pack_hi16(float hi, float lo) {
    return (__float_as_uint(hi) & 0xFFFF0000u) | (__float_as_uint(lo) >> 16);
}
__device__ __forceinline__ bf16x8 pack_bf16x8(float4 lo, float4 hi) {
    union { bf16x8 v; unsigned u[4]; } r;
    r.u[0] = pack_hi16(lo.y, lo.x);
    r.u[1] = pack_hi16(lo.w, lo.z);
    r.u[2] = pack_hi16(hi.y, hi.x);
    r.u[3] = pack_hi16(hi.w, hi.z);
    return r.v;
}

// async global->LDS DMA, 16 B per lane; LDS dest must be wave-uniform-base + lane*16
__device__ __forceinline__ void gld16(const float* g, float* l) {
    __builtin_amdgcn_global_load_lds(
        (const __attribute__((address_space(1))) void*)g,
        (__attribute__((address_space(3))) void*)l, 16, 0, 0);
}

// ---------------- Kernel 1: bf16 MFMA GEMM -> hp (row-major) + haT (transposed) ----------------
__global__ __launch_bounds__(256)
void gemm_mfma(const float* __restrict__ X,
               const float* __restrict__ Wprd,
               const float* __restrict__ Warg,
               const float* __restrict__ bprd,
               const float* __restrict__ barg,
               float* __restrict__ hp_out,
               float* __restrict__ haT,
               float* __restrict__ accum)
{
    if (blockIdx.x == 0 && blockIdx.y == 0 && threadIdx.x == 0) {
        accum[0] = 0.f; accum[1] = 0.f;
        ((unsigned*)accum)[2] = 0u;      // completion counter
    }
    const int bm   = blockIdx.x;          // 0..3   (64 rows)
    const int bn   = blockIdx.y;          // 0..143 (32 cols)
    const int wave = threadIdx.x >> 6;
    const int lane = threadIdx.x & 63;
    const int l16  = lane & 15;
    const int quad = lane >> 4;

    const float* Wsrc; const float* bsrc;
    const int nb = bn * 32;
    if (nb < Hh) { Wsrc = Wprd + (size_t)nb * Hh;        bsrc = bprd + nb; }
    else         { Wsrc = Warg + (size_t)(nb - Hh) * Hh; bsrc = barg + (nb - Hh); }

    const int m_g = bm * 64 + wave * 16 + l16;
    const float* arow  = X    + (size_t)m_g * Hh + quad * 8;
    const float* brow0 = Wsrc + (size_t)l16 * Hh + quad * 8;
    const float* brow1 = Wsrc + (size_t)(16 + l16) * Hh + quad * 8;

    f32x4 acc0 = {0.f, 0.f, 0.f, 0.f};
    f32x4 acc1 = {0.f, 0.f, 0.f, 0.f};

    float4 a0  = *(const float4*)(arow);
    float4 a1  = *(const float4*)(arow + 4);
    float4 b00 = *(const float4*)(brow0);
    float4 b01 = *(const float4*)(brow0 + 4);
    float4 b10 = *(const float4*)(brow1);
    float4 b11 = *(const float4*)(brow1 + 4);

    #pragma unroll 4
    for (int k = 0; k < Hh; k += 32) {
        const int kn = (k + 32 < Hh) ? k + 32 : 0;
        float4 na0  = *(const float4*)(arow  + kn);
        float4 na1  = *(const float4*)(arow  + kn + 4);
        float4 nb00 = *(const float4*)(brow0 + kn);
        float4 nb01 = *(const float4*)(brow0 + kn + 4);
        float4 nb10 = *(const float4*)(brow1 + kn);
        float4 nb11 = *(const float4*)(brow1 + kn + 4);
        bf16x8 af  = pack_bf16x8(a0,  a1);
        bf16x8 bf0 = pack_bf16x8(b00, b01);
        bf16x8 bf1 = pack_bf16x8(b10, b11);
        acc0 = __builtin_amdgcn_mfma_f32_16x16x32_bf16(af, bf0, acc0, 0, 0, 0);
        acc1 = __builtin_amdgcn_mfma_f32_16x16x32_bf16(af, bf1, acc1, 0, 0, 0);
        a0 = na0; a1 = na1; b00 = nb00; b01 = nb01; b10 = nb10; b11 = nb11;
    }

    const float sb0 = SCALE * bsrc[l16];
    const float sb1 = SCALE * bsrc[16 + l16];
    const int row = bm * 64 + wave * 16 + quad * 4;

    if (nb < Hh) {   // hp: row-major [m][h]
        #pragma unroll
        for (int r = 0; r < 4; ++r) {
            const int mm = row + r;
            hp_out[(size_t)mm * Hh + nb + l16]      = SCALE * acc0[r] + sb0;
            hp_out[(size_t)mm * Hh + nb + 16 + l16] = SCALE * acc1[r] + sb1;
        }
    } else {         // ha -> haT[b][c][hg][a][hl]
        const int q  = nb - Hh;
        const int cU = q / Hh;
        const int h0 = q % Hh;
        const int off0 = cU * HA_C + ((h0 + l16) >> 2) * HA_HG + (l16 & 3);
        const int off1 = off0 + 4 * HA_HG;
        #pragma unroll
        for (int r = 0; r < 4; ++r) {
            const int mm = row + r;
            const int base = (mm >> 7) * HA_B + (mm & 127) * 4;
            haT[base + off0] = SCALE * acc0[r] + sb0;
            haT[base + off1] = SCALE * acc1[r] + sb1;
        }
    }
}

// ---------------- Kernel 2: biaffine via global_load_lds double-buffer ----------------
// Grid 1280 = (bp, c). Block 256 thr: tid = hh*128 + a; each thread reduces 384 h.
// logit = sumW[c] - 2*sum_h wc[h]*rcp(exp2(hp'+ha')+1) + maskneg[a]
__global__ __launch_bounds__(256)
void biaffine_loss(const float* __restrict__ hp_all,
                   const float* __restrict__ haT,
                   const float* __restrict__ Wout,
                   const int* __restrict__ ng,
                   const int* __restrict__ att,
                   const float* __restrict__ target,
                   float* __restrict__ out_logits,
                   float* __restrict__ accum,
                   float* __restrict__ out_loss)
{
    __shared__ float ha_s[2][CHUNK_F];   // 2 x 12 KB double buffer
    __shared__ float hp_s[Hh];
    __shared__ float wc_s[Hh];
    __shared__ float partial[Ss];
    __shared__ float maskneg[Ss];
    __shared__ float redmax[2];
    __shared__ float red3[2][3];
    __shared__ float swr_s;

    const int bpc = blockIdx.x;
    const int bp  = bpc / Cc;
    const int c   = bpc - bp * Cc;
    const int b   = bp >> 7;
    const int tid = threadIdx.x;
    const int a   = tid & (Ss - 1);
    const int hh  = tid >> 7;          // 0/1: h-half (wave-uniform: waves 0,1 -> 0; 2,3 -> 1)
    const int lane = tid & 63;

    const float* haBase = haT + (size_t)b * HA_B + (size_t)c * HA_C;

    // DMA chunk 0 into buffer 0 (cannot be sunk by the compiler)
    {
        const float* s0 = haBase + tid * 4;
        float* d0 = &ha_s[0][tid * 4];
        gld16(s0,        d0);
        gld16(s0 + 1024, d0 + 1024);
        gld16(s0 + 2048, d0 + 2048);
    }

    // stage hp row + wc row into LDS (coalesced), mask
    for (int i = tid; i < Hh; i += 256) {
        hp_s[i] = hp_all[(size_t)bp * Hh + i];
        wc_s[i] = Wout[(size_t)c * Hh + i];
    }
    if (tid < Ss) {
        int any = 0;
        if (att[b * Ss + tid] > 0) {
            const int* ngp = ng + (size_t)bp * Cc * Ss + tid;
            #pragma unroll
            for (int cc = 0; cc < Cc; ++cc) any |= ngp[cc * Ss];
        }
        maskneg[tid] = any ? 0.0f : NEGV;
    }
    __syncthreads();   // compiler drains vmcnt (chunk 0 DMA + staging) here

    if (tid < 64) {    // wave 0: sumW[c]
        float s = 0.f;
        #pragma unroll
        for (int i = 0; i < Hh / 64; ++i) s += wc_s[tid + i * 64];
        #pragma unroll
        for (int off = 32; off; off >>= 1) s += __shfl_xor(s, off, 64);
        if (tid == 0) swr_s = s;
    }

    float ac0 = 0.f, ac1 = 0.f, ac2 = 0.f, ac3 = 0.f;
    for (int it = 0; it < NCHUNK; ++it) {
        if (it + 1 < NCHUNK) {         // DMA next chunk into the other buffer
            const float* sn = haBase + (it + 1) * CHUNK_F + tid * 4;
            float* dn = &ha_s[(it + 1) & 1][tid * 4];
            gld16(sn,        dn);
            gld16(sn + 1024, dn + 1024);
            gld16(sn + 2048, dn + 2048);
        }
        const float* cbuf = ha_s[it & 1];
        #pragma unroll
        for (int j = 0; j < 3; ++j) {
            const int hgl = hh * 3 + j;
            float4 gv = *(const float4*)(cbuf + hgl * 512 + a * 4);   // b128, conflict-free
            const int hx = it * CHUNK_H + hgl * 4;
            float4 p = *(const float4*)(hp_s + hx);   // wave-uniform broadcast
            float4 w = *(const float4*)(wc_s + hx);
            float r0 = __builtin_amdgcn_rcpf(__builtin_amdgcn_exp2f(p.x + gv.x) + 1.0f);
            float r1 = __builtin_amdgcn_rcpf(__builtin_amdgcn_exp2f(p.y + gv.y) + 1.0f);
            float r2 = __builtin_amdgcn_rcpf(__builtin_amdgcn_exp2f(p.z + gv.z) + 1.0f);
            float r3 = __builtin_amdgcn_rcpf(__builtin_amdgcn_exp2f(p.w + gv.w) + 1.0f);
            ac0 = fmaf(w.x, r0, ac0);
            ac1 = fmaf(w.y, r1, ac1);
            ac2 = fmaf(w.z, r2, ac2);
            ac3 = fmaf(w.w, r3, ac3);
        }
        __syncthreads();   // waits next-chunk DMA + all reads of cbuf done
    }

    const float psum = (ac0 + ac1) + (ac2 + ac3);
    if (hh == 1) partial[a] = psum;
    __syncthreads();

    float logit = 0.f;
    if (hh == 0) {
        logit = swr_s - 2.0f * (psum + partial[a]) + maskneg[a];
        out_logits[((size_t)bp * Cc + c) * Ss + a] = logit;
        float mx = logit;
        #pragma unroll
        for (int off = 32; off; off >>= 1) mx = fmaxf(mx, __shfl_xor(mx, off, 64));
        if (lane == 0) redmax[tid >> 6] = mx;
    }
    __syncthreads();

    if (hh == 0) {
        const float rm = fmaxf(redmax[0], redmax[1]);
        const float e  = __builtin_amdgcn_exp2f((logit - rm) * 1.4426950408889634f);
        const float tg = target[((size_t)bp * Cc + c) * Ss + a];
        float se = e, st = tg, sx = tg * logit;
        #pragma unroll
        for (int off = 32; off; off >>= 1) {
            se += __shfl_xor(se, off, 64);
            st += __shfl_xor(st, off, 64);
            sx += __shfl_xor(sx, off, 64);
        }
        if (lane == 0) { red3[tid >> 6][0] = se; red3[tid >> 6][1] = st; red3[tid >> 6][2] = sx; }
    }
    __syncthreads();

    if (tid == 0) {
        const float rm = fmaxf(redmax[0], redmax[1]);
        const float SE = red3[0][0] + red3[1][0];
        const float ST = red3[0][1] + red3[1][1];
        const float SX = red3[0][2] + red3[1][2];
        const float lse = rm + __builtin_amdgcn_logf(SE) * 0.6931471805599453f;
        atomicAdd(&accum[0], lse * ST - SX);
        atomicAdd(&accum[1], ST);
        __threadfence();
        const unsigned old = atomicAdd((unsigned*)(accum + 2), 1u);
        if (old == (unsigned)(Mm * Cc - 1)) {       // last block: finalize loss
            const float n = atomicAdd(&accum[0], 0.0f);
            const float d = atomicAdd(&accum[1], 0.0f);
            out_loss[0] = n / d;
        }
    }
}

extern "C" void kernel_launch(void* const* d_in, const int* in_sizes, int n_in,
                              void* d_out, int out_size, void* d_ws, size_t ws_size,
                              hipStream_t stream) {
    const float* seq    = (const float*)d_in[0];
    const int*   att    = (const int*)  d_in[1];
    const int*   ng     = (const int*)  d_in[2];
    const float* target = (const float*)d_in[3];
    const float* Wprd   = (const float*)d_in[4];
    const float* bprd   = (const float*)d_in[5];
    const float* Warg   = (const float*)d_in[6];
    const float* barg   = (const float*)d_in[7];
    const float* Wout   = (const float*)d_in[8];

    float* out    = (float*)d_out;
    float* hp_out = (float*)d_ws;                        // 256*768 floats
    float* haT    = hp_out + (size_t)Mm * Hh;            // 2*491520 floats
    float* accum  = haT + 2 * (size_t)HA_B;              // 3 slots

    gemm_mfma<<<dim3(4, 144), 256, 0, stream>>>(seq, Wprd, Warg, bprd, barg,
                                                hp_out, haT, accum);
    biaffine_loss<<<dim3(Mm * Cc), 256, 0, stream>>>(hp_out, haT, Wout, ng, att, target,
                                                     out + 1, accum, out);
}

// Round 7
// 188.405 us; speedup vs baseline: 1.0743x; 1.0743x over previous
//
#include <hip/hip_runtime.h>
#include <math.h>

#define Bb 2
#define Ss 128
#define Hh 768
#define Cc 5
#define Mm 256       // Bb*Ss
#define NEGV -1024.0f
#define SCALE 2.8853900817779268f   // 2/ln(2): stored pre-scaled so exp2(hp'+ha') = e^{2x}

// haT layout: [b][c][hg][a][hl], hg=h/4, hl=h&3
#define HA_B  491520   // 5*192*128*4
#define HA_C  98304    // 192*128*4
#define HA_HG 512      // 128*4

#define PT 2           // p-tile per block
#define CHUNK_H 24
#define CHUNK_F 3072   // 24*128 floats = 12 KB
#define NCHUNK 32      // 768/24
#define NBLK (Mm / PT * Cc)   // 640

typedef __attribute__((ext_vector_type(8))) short bf16x8;
typedef __attribute__((ext_vector_type(4))) float f32x4;

__device__ __forceinline__ unsigned pack_hi16(float hi, float lo) {
    return (__float_as_uint(hi) & 0xFFFF0000u) | (__float_as_uint(lo) >> 16);
}
__device__ __forceinline__ bf16x8 pack_bf16x8(float4 lo, float4 hi) {
    union { bf16x8 v; unsigned u[4]; } r;
    r.u[0] = pack_hi16(lo.y, lo.x);
    r.u[1] = pack_hi16(lo.w, lo.z);
    r.u[2] = pack_hi16(hi.y, hi.x);
    r.u[3] = pack_hi16(hi.w, hi.z);
    return r.v;
}

// async global->LDS DMA, 16 B per lane; LDS dest must be wave-uniform-base + lane*16
__device__ __forceinline__ void gld16(const float* g, float* l) {
    __builtin_amdgcn_global_load_lds(
        (const __attribute__((address_space(1))) void*)g,
        (__attribute__((address_space(3))) void*)l, 16, 0, 0);
}

// ---------------- Kernel 1: bf16 MFMA GEMM -> hp (row-major) + haT (transposed) ----------------
__global__ __launch_bounds__(256)
void gemm_mfma(const float* __restrict__ X,
               const float* __restrict__ Wprd,
               const float* __restrict__ Warg,
               const float* __restrict__ bprd,
               const float* __restrict__ barg,
               float* __restrict__ hp_out,
               float* __restrict__ haT,
               float* __restrict__ accum)
{
    if (blockIdx.x == 0 && blockIdx.y == 0 && threadIdx.x == 0) {
        accum[0] = 0.f; accum[1] = 0.f;
        ((unsigned*)accum)[2] = 0u;      // completion counter
    }
    const int bm   = blockIdx.x;          // 0..3   (64 rows)
    const int bn   = blockIdx.y;          // 0..143 (32 cols)
    const int wave = threadIdx.x >> 6;
    const int lane = threadIdx.x & 63;
    const int l16  = lane & 15;
    const int quad = lane >> 4;

    const float* Wsrc; const float* bsrc;
    const int nb = bn * 32;
    if (nb < Hh) { Wsrc = Wprd + (size_t)nb * Hh;        bsrc = bprd + nb; }
    else         { Wsrc = Warg + (size_t)(nb - Hh) * Hh; bsrc = barg + (nb - Hh); }

    const int m_g = bm * 64 + wave * 16 + l16;
    const float* arow  = X    + (size_t)m_g * Hh + quad * 8;
    const float* brow0 = Wsrc + (size_t)l16 * Hh + quad * 8;
    const float* brow1 = Wsrc + (size_t)(16 + l16) * Hh + quad * 8;

    f32x4 acc0 = {0.f, 0.f, 0.f, 0.f};
    f32x4 acc1 = {0.f, 0.f, 0.f, 0.f};

    float4 a0  = *(const float4*)(arow);
    float4 a1  = *(const float4*)(arow + 4);
    float4 b00 = *(const float4*)(brow0);
    float4 b01 = *(const float4*)(brow0 + 4);
    float4 b10 = *(const float4*)(brow1);
    float4 b11 = *(const float4*)(brow1 + 4);

    #pragma unroll 4
    for (int k = 0; k < Hh; k += 32) {
        const int kn = (k + 32 < Hh) ? k + 32 : 0;
        float4 na0  = *(const float4*)(arow  + kn);
        float4 na1  = *(const float4*)(arow  + kn + 4);
        float4 nb00 = *(const float4*)(brow0 + kn);
        float4 nb01 = *(const float4*)(brow0 + kn + 4);
        float4 nb10 = *(const float4*)(brow1 + kn);
        float4 nb11 = *(const float4*)(brow1 + kn + 4);
        bf16x8 af  = pack_bf16x8(a0,  a1);
        bf16x8 bf0 = pack_bf16x8(b00, b01);
        bf16x8 bf1 = pack_bf16x8(b10, b11);
        acc0 = __builtin_amdgcn_mfma_f32_16x16x32_bf16(af, bf0, acc0, 0, 0, 0);
        acc1 = __builtin_amdgcn_mfma_f32_16x16x32_bf16(af, bf1, acc1, 0, 0, 0);
        a0 = na0; a1 = na1; b00 = nb00; b01 = nb01; b10 = nb10; b11 = nb11;
    }

    const float sb0 = SCALE * bsrc[l16];
    const float sb1 = SCALE * bsrc[16 + l16];
    const int row = bm * 64 + wave * 16 + quad * 4;

    if (nb < Hh) {   // hp: row-major [m][h]
        #pragma unroll
        for (int r = 0; r < 4; ++r) {
            const int mm = row + r;
            hp_out[(size_t)mm * Hh + nb + l16]      = SCALE * acc0[r] + sb0;
            hp_out[(size_t)mm * Hh + nb + 16 + l16] = SCALE * acc1[r] + sb1;
        }
    } else {         // ha -> haT[b][c][hg][a][hl]
        const int q  = nb - Hh;
        const int cU = q / Hh;
        const int h0 = q % Hh;
        const int off0 = cU * HA_C + ((h0 + l16) >> 2) * HA_HG + (l16 & 3);
        const int off1 = off0 + 4 * HA_HG;
        #pragma unroll
        for (int r = 0; r < 4; ++r) {
            const int mm = row + r;
            const int base = (mm >> 7) * HA_B + (mm & 127) * 4;
            haT[base + off0] = SCALE * acc0[r] + sb0;
            haT[base + off1] = SCALE * acc1[r] + sb1;
        }
    }
}

// ---------------- Kernel 2: biaffine, p-tiled (PT=2) DMA double-buffer ----------------
// Grid 640 = (p-tile, c). Block 256 thr: tid = hh*128 + a. Each thread: PT accumulators,
// 384 h (its half). logit[p] = sumW[c] - 2*sum_h wc[h]*rcp(exp2(hp'[p,h]+ha')+1) + maskneg[p][a]
__global__ __launch_bounds__(256)
void biaffine_loss(const float* __restrict__ hp_all,
                   const float* __restrict__ haT,
                   const float* __restrict__ Wout,
                   const int* __restrict__ ng,
                   const int* __restrict__ att,
                   const float* __restrict__ target,
                   float* __restrict__ out_logits,
                   float* __restrict__ accum,
                   float* __restrict__ out_loss)
{
    __shared__ float ha_s[2][CHUNK_F];   // 2 x 12 KB double buffer
    __shared__ float hp_s[PT][Hh];
    __shared__ float wc_s[Hh];
    __shared__ float partial[PT][Ss];
    __shared__ float maskneg[PT][Ss];
    __shared__ float redmax[PT][2];
    __shared__ float red3[PT][2][3];
    __shared__ float swr_s;

    const int pt  = blockIdx.x / Cc;     // 0..127
    const int c   = blockIdx.x - pt * Cc;
    const int bp0 = pt * PT;             // first bp of tile (same b for whole tile)
    const int b   = bp0 >> 7;
    const int tid = threadIdx.x;
    const int a   = tid & (Ss - 1);
    const int hh  = tid >> 7;            // 0/1: h-half (waves 0,1 -> 0; 2,3 -> 1)
    const int lane = tid & 63;

    const float* haBase = haT + (size_t)b * HA_B + (size_t)c * HA_C;

    // DMA chunk 0 into buffer 0 (side-effecting: cannot be sunk)
    {
        const float* s0 = haBase + tid * 4;
        float* d0 = &ha_s[0][tid * 4];
        gld16(s0,        d0);
        gld16(s0 + 1024, d0 + 1024);
        gld16(s0 + 2048, d0 + 2048);
    }

    // stage hp rows (PT contiguous rows) + wc row into LDS (coalesced)
    for (int i = tid; i < PT * Hh; i += 256) ((float*)hp_s)[i] = hp_all[(size_t)bp0 * Hh + i];
    for (int i = tid; i < Hh; i += 256)      wc_s[i] = Wout[(size_t)c * Hh + i];
    {
        const int p_i = tid >> 7;        // 0..PT-1
        const int aa  = tid & (Ss - 1);
        int any = 0;
        if (att[b * Ss + aa] > 0) {
            const int* ngp = ng + (size_t)(bp0 + p_i) * Cc * Ss + aa;
            #pragma unroll
            for (int cc = 0; cc < Cc; ++cc) any |= ngp[cc * Ss];
        }
        maskneg[p_i][aa] = any ? 0.0f : NEGV;
    }
    __syncthreads();   // drains chunk-0 DMA + staging

    if (tid < 64) {    // wave 0: sumW[c]
        float s = 0.f;
        #pragma unroll
        for (int i = 0; i < Hh / 64; ++i) s += wc_s[tid + i * 64];
        #pragma unroll
        for (int off = 32; off; off >>= 1) s += __shfl_xor(s, off, 64);
        if (tid == 0) swr_s = s;
    }

    float ac[PT][2];
    #pragma unroll
    for (int p = 0; p < PT; ++p) { ac[p][0] = 0.f; ac[p][1] = 0.f; }

    for (int it = 0; it < NCHUNK; ++it) {
        if (it + 1 < NCHUNK) {           // DMA next chunk into the other buffer
            const float* sn = haBase + (it + 1) * CHUNK_F + tid * 4;
            float* dn = &ha_s[(it + 1) & 1][tid * 4];
            gld16(sn,        dn);
            gld16(sn + 1024, dn + 1024);
            gld16(sn + 2048, dn + 2048);
        }
        const float* cbuf = ha_s[it & 1];
        #pragma unroll
        for (int j = 0; j < 3; ++j) {
            const int hgl = hh * 3 + j;
            float4 gv = *(const float4*)(cbuf + hgl * 512 + a * 4);   // b128, phased-contig
            const int hx = it * CHUNK_H + hgl * 4;
            float4 w = *(const float4*)(wc_s + hx);
            #pragma unroll
            for (int p = 0; p < PT; ++p) {
                float4 hpv = *(const float4*)(&hp_s[p][hx]);   // uniform broadcast
                float r0 = __builtin_amdgcn_rcpf(__builtin_amdgcn_exp2f(hpv.x + gv.x) + 1.0f);
                float r1 = __builtin_amdgcn_rcpf(__builtin_amdgcn_exp2f(hpv.y + gv.y) + 1.0f);
                float r2 = __builtin_amdgcn_rcpf(__builtin_amdgcn_exp2f(hpv.z + gv.z) + 1.0f);
                float r3 = __builtin_amdgcn_rcpf(__builtin_amdgcn_exp2f(hpv.w + gv.w) + 1.0f);
                ac[p][0] = fmaf(w.x, r0, ac[p][0]);
                ac[p][1] = fmaf(w.y, r1, ac[p][1]);
                ac[p][0] = fmaf(w.z, r2, ac[p][0]);
                ac[p][1] = fmaf(w.w, r3, ac[p][1]);
            }
        }
        __syncthreads();
    }

    if (hh == 1) {
        #pragma unroll
        for (int p = 0; p < PT; ++p) partial[p][a] = ac[p][0] + ac[p][1];
    }
    __syncthreads();

    float logit[PT];
    const int wv = tid >> 6;             // 0/1 for hh==0 threads
    if (hh == 0) {
        #pragma unroll
        for (int p = 0; p < PT; ++p) {
            logit[p] = swr_s - 2.0f * (ac[p][0] + ac[p][1] + partial[p][a]) + maskneg[p][a];
            out_logits[((size_t)(bp0 + p) * Cc + c) * Ss + a] = logit[p];
            float mx = logit[p];
            #pragma unroll
            for (int off = 32; off; off >>= 1) mx = fmaxf(mx, __shfl_xor(mx, off, 64));
            if (lane == 0) redmax[p][wv] = mx;
        }
    }
    __syncthreads();

    if (hh == 0) {
        #pragma unroll
        for (int p = 0; p < PT; ++p) {
            const float rm = fmaxf(redmax[p][0], redmax[p][1]);
            const float e  = __builtin_amdgcn_exp2f((logit[p] - rm) * 1.4426950408889634f);
            const float tg = target[((size_t)(bp0 + p) * Cc + c) * Ss + a];
            float se = e, st = tg, sx = tg * logit[p];
            #pragma unroll
            for (int off = 32; off; off >>= 1) {
                se += __shfl_xor(se, off, 64);
                st += __shfl_xor(st, off, 64);
                sx += __shfl_xor(sx, off, 64);
            }
            if (lane == 0) { red3[p][wv][0] = se; red3[p][wv][1] = st; red3[p][wv][2] = sx; }
        }
    }
    __syncthreads();

    if (tid == 0) {
        float nsum = 0.f, dsum = 0.f;
        #pragma unroll
        for (int p = 0; p < PT; ++p) {
            const float rm = fmaxf(redmax[p][0], redmax[p][1]);
            const float SE = red3[p][0][0] + red3[p][1][0];
            const float ST = red3[p][0][1] + red3[p][1][1];
            const float SX = red3[p][0][2] + red3[p][1][2];
            const float lse = rm + __builtin_amdgcn_logf(SE) * 0.6931471805599453f;
            nsum += lse * ST - SX;
            dsum += ST;
        }
        atomicAdd(&accum[0], nsum);
        atomicAdd(&accum[1], dsum);
        __threadfence();
        const unsigned old = atomicAdd((unsigned*)(accum + 2), 1u);
        if (old == (unsigned)(NBLK - 1)) {          // last block: finalize loss
            const float n = atomicAdd(&accum[0], 0.0f);
            const float d = atomicAdd(&accum[1], 0.0f);
            out_loss[0] = n / d;
        }
    }
}

extern "C" void kernel_launch(void* const* d_in, const int* in_sizes, int n_in,
                              void* d_out, int out_size, void* d_ws, size_t ws_size,
                              hipStream_t stream) {
    const float* seq    = (const float*)d_in[0];
    const int*   att    = (const int*)  d_in[1];
    const int*   ng     = (const int*)  d_in[2];
    const float* target = (const float*)d_in[3];
    const float* Wprd   = (const float*)d_in[4];
    const float* bprd   = (const float*)d_in[5];
    const float* Warg   = (const float*)d_in[6];
    const float* barg   = (const float*)d_in[7];
    const float* Wout   = (const float*)d_in[8];

    float* out    = (float*)d_out;
    float* hp_out = (float*)d_ws;                        // 256*768 floats
    float* haT    = hp_out + (size_t)Mm * Hh;            // 2*491520 floats
    float* accum  = haT + 2 * (size_t)HA_B;              // 3 slots

    gemm_mfma<<<dim3(4, 144), 256, 0, stream>>>(seq, Wprd, Warg, bprd, barg,
                                                hp_out, haT, accum);
    biaffine_loss<<<dim3(NBLK), 256, 0, stream>>>(hp_out, haT, Wout, ng, att, target,
                                                  out + 1, accum, out);
}

// Round 9
// 177.664 us; speedup vs baseline: 1.1392x; 1.0605x over previous
//
#include <hip/hip_runtime.h>
#include <math.h>

#define Bb 2
#define Ss 128
#define Hh 768
#define Cc 5
#define Mm 256       // Bb*Ss
#define NEGV -1024.0f
#define SCALE 2.8853900817779268f   // 2/ln(2): stored pre-scaled so exp2(hp'+ha') = e^{2x}

// haT layout: [b][c][hg][a][hl], hg=h/4, hl=h&3
#define HA_B  491520   // 5*192*128*4
#define HA_C  98304    // 192*128*4

#define PT 2                  // p-tile per block
#define NBLK (Mm / PT * Cc)   // 640

typedef __attribute__((ext_vector_type(8))) short bf16x8;
typedef __attribute__((ext_vector_type(4))) float f32x4;

__device__ __forceinline__ unsigned pack_hi16(float hi, float lo) {
    return (__float_as_uint(hi) & 0xFFFF0000u) | (__float_as_uint(lo) >> 16);
}
__device__ __forceinline__ bf16x8 pack_bf16x8(float4 lo, float4 hi) {
    union { bf16x8 v; unsigned u[4]; } r;
    r.u[0] = pack_hi16(lo.y, lo.x);
    r.u[1] = pack_hi16(lo.w, lo.z);
    r.u[2] = pack_hi16(hi.y, hi.x);
    r.u[3] = pack_hi16(hi.w, hi.z);
    return r.v;
}

// ---------------- Kernel 1: bf16 MFMA GEMM -> hp (row-major) + haT (transposed) ----------------
__global__ __launch_bounds__(256)
void gemm_mfma(const float* __restrict__ X,
               const float* __restrict__ Wprd,
               const float* __restrict__ Warg,
               const float* __restrict__ bprd,
               const float* __restrict__ barg,
               float* __restrict__ hp_out,
               float* __restrict__ haT,
               float* __restrict__ accum)
{
    if (blockIdx.x == 0 && blockIdx.y == 0 && threadIdx.x == 0) {
        accum[0] = 0.f; accum[1] = 0.f;
        ((unsigned*)accum)[2] = 0u;      // completion counter
    }
    const int bm   = blockIdx.x;          // 0..3   (64 rows)
    const int bn   = blockIdx.y;          // 0..143 (32 cols)
    const int wave = threadIdx.x >> 6;
    const int lane = threadIdx.x & 63;
    const int l16  = lane & 15;
    const int quad = lane >> 4;

    const float* Wsrc; const float* bsrc;
    const int nb = bn * 32;
    if (nb < Hh) { Wsrc = Wprd + (size_t)nb * Hh;        bsrc = bprd + nb; }
    else         { Wsrc = Warg + (size_t)(nb - Hh) * Hh; bsrc = barg + (nb - Hh); }

    const int m_g = bm * 64 + wave * 16 + l16;
    const float* arow  = X    + (size_t)m_g * Hh + quad * 8;
    const float* brow0 = Wsrc + (size_t)l16 * Hh + quad * 8;
    const float* brow1 = Wsrc + (size_t)(16 + l16) * Hh + quad * 8;

    f32x4 acc0 = {0.f, 0.f, 0.f, 0.f};
    f32x4 acc1 = {0.f, 0.f, 0.f, 0.f};

    float4 a0  = *(const float4*)(arow);
    float4 a1  = *(const float4*)(arow + 4);
    float4 b00 = *(const float4*)(brow0);
    float4 b01 = *(const float4*)(brow0 + 4);
    float4 b10 = *(const float4*)(brow1);
    float4 b11 = *(const float4*)(brow1 + 4);

    #pragma unroll 4
    for (int k = 0; k < Hh; k += 32) {
        const int kn = (k + 32 < Hh) ? k + 32 : 0;
        float4 na0  = *(const float4*)(arow  + kn);
        float4 na1  = *(const float4*)(arow  + kn + 4);
        float4 nb00 = *(const float4*)(brow0 + kn);
        float4 nb01 = *(const float4*)(brow0 + kn + 4);
        float4 nb10 = *(const float4*)(brow1 + kn);
        float4 nb11 = *(const float4*)(brow1 + kn + 4);
        bf16x8 af  = pack_bf16x8(a0,  a1);
        bf16x8 bf0 = pack_bf16x8(b00, b01);
        bf16x8 bf1 = pack_bf16x8(b10, b11);
        acc0 = __builtin_amdgcn_mfma_f32_16x16x32_bf16(af, bf0, acc0, 0, 0, 0);
        acc1 = __builtin_amdgcn_mfma_f32_16x16x32_bf16(af, bf1, acc1, 0, 0, 0);
        a0 = na0; a1 = na1; b00 = nb00; b01 = nb01; b10 = nb10; b11 = nb11;
    }

    const float sb0 = SCALE * bsrc[l16];
    const float sb1 = SCALE * bsrc[16 + l16];
    const int row = bm * 64 + wave * 16 + quad * 4;

    if (nb < Hh) {   // hp: row-major [m][h]
        #pragma unroll
        for (int r = 0; r < 4; ++r) {
            const int mm = row + r;
            hp_out[(size_t)mm * Hh + nb + l16]      = SCALE * acc0[r] + sb0;
            hp_out[(size_t)mm * Hh + nb + 16 + l16] = SCALE * acc1[r] + sb1;
        }
    } else {         // ha -> haT[b][c][hg][a][hl]
        const int q  = nb - Hh;
        const int cU = q / Hh;
        const int h0 = q % Hh;
        const int off0 = cU * HA_C + ((h0 + l16) >> 2) * 512 + (l16 & 3);
        const int off1 = off0 + 4 * 512;
        #pragma unroll
        for (int r = 0; r < 4; ++r) {
            const int mm = row + r;
            const int base = (mm >> 7) * HA_B + (mm & 127) * 4;
            haT[base + off0] = SCALE * acc0[r] + sb0;
            haT[base + off1] = SCALE * acc1[r] + sb1;
        }
    }
}

// ---------------- Kernel 2: biaffine, sched_barrier-pinned ping-pong stream ----------------
// Grid 640 = (p-tile, c). Block 256: tid = hh*128 + a; thread reduces its 384-h half (96 float4)
// for PT=2 p's. Plain dwordx4 loads in groups of 8, region-fenced so the scheduler cannot sink
// them; backend emits fine-grained vmcnt(15..8) waits -> 8-16 loads always in flight.
#define SB __builtin_amdgcn_sched_barrier(0);

#define LOADG(R, g) \
    R##0 = hap4[((g)*8+0)*128]; R##1 = hap4[((g)*8+1)*128]; \
    R##2 = hap4[((g)*8+2)*128]; R##3 = hap4[((g)*8+3)*128]; \
    R##4 = hap4[((g)*8+4)*128]; R##5 = hap4[((g)*8+5)*128]; \
    R##6 = hap4[((g)*8+6)*128]; R##7 = hap4[((g)*8+7)*128];

#define C1(gv, hx) { \
    const float4 w   = *(const float4*)(wc_s + (hx)); \
    const float4 h0v = *(const float4*)(&hp_s[0][hx]); \
    const float4 h1v = *(const float4*)(&hp_s[1][hx]); \
    float r; \
    r = __builtin_amdgcn_rcpf(__builtin_amdgcn_exp2f(h0v.x + (gv).x) + 1.0f); ac00 = fmaf(w.x, r, ac00); \
    r = __builtin_amdgcn_rcpf(__builtin_amdgcn_exp2f(h0v.y + (gv).y) + 1.0f); ac01 = fmaf(w.y, r, ac01); \
    r = __builtin_amdgcn_rcpf(__builtin_amdgcn_exp2f(h0v.z + (gv).z) + 1.0f); ac00 = fmaf(w.z, r, ac00); \
    r = __builtin_amdgcn_rcpf(__builtin_amdgcn_exp2f(h0v.w + (gv).w) + 1.0f); ac01 = fmaf(w.w, r, ac01); \
    r = __builtin_amdgcn_rcpf(__builtin_amdgcn_exp2f(h1v.x + (gv).x) + 1.0f); ac10 = fmaf(w.x, r, ac10); \
    r = __builtin_amdgcn_rcpf(__builtin_amdgcn_exp2f(h1v.y + (gv).y) + 1.0f); ac11 = fmaf(w.y, r, ac11); \
    r = __builtin_amdgcn_rcpf(__builtin_amdgcn_exp2f(h1v.z + (gv).z) + 1.0f); ac10 = fmaf(w.z, r, ac10); \
    r = __builtin_amdgcn_rcpf(__builtin_amdgcn_exp2f(h1v.w + (gv).w) + 1.0f); ac11 = fmaf(w.w, r, ac11); \
}

#define CONSUMEG(R, g) \
    C1(R##0, hbase + (g)*32 + 0)  C1(R##1, hbase + (g)*32 + 4)  \
    C1(R##2, hbase + (g)*32 + 8)  C1(R##3, hbase + (g)*32 + 12) \
    C1(R##4, hbase + (g)*32 + 16) C1(R##5, hbase + (g)*32 + 20) \
    C1(R##6, hbase + (g)*32 + 24) C1(R##7, hbase + (g)*32 + 28)

__global__ __launch_bounds__(256, 4)
void biaffine_loss(const float* __restrict__ hp_all,
                   const float* __restrict__ haT,
                   const float* __restrict__ Wout,
                   const int* __restrict__ ng,
                   const int* __restrict__ att,
                   const float* __restrict__ target,
                   float* __restrict__ out_logits,
                   float* __restrict__ accum,
                   float* __restrict__ out_loss)
{
    __shared__ float hp_s[PT][Hh];
    __shared__ float wc_s[Hh];
    __shared__ float partial[PT][Ss];
    __shared__ float maskneg[PT][Ss];
    __shared__ float redmax[PT][2];
    __shared__ float red3[PT][2][3];
    __shared__ float swr_s;

    const int pt  = blockIdx.x / Cc;     // 0..127
    const int c   = blockIdx.x - pt * Cc;
    const int bp0 = pt * PT;
    const int b   = bp0 >> 7;
    const int tid = threadIdx.x;
    const int a   = tid & (Ss - 1);
    const int hh  = tid >> 7;            // 0/1: h-half (waves 0,1 -> 0; 2,3 -> 1)
    const int lane = tid & 63;

    // stage hp rows + wc row into LDS (coalesced); mask
    for (int i = tid; i < PT * Hh; i += 256) ((float*)hp_s)[i] = hp_all[(size_t)bp0 * Hh + i];
    for (int i = tid; i < Hh; i += 256)      wc_s[i] = Wout[(size_t)c * Hh + i];
    {
        const int p_i = tid >> 7;
        const int aa  = tid & (Ss - 1);
        int any = 0;
        if (att[b * Ss + aa] > 0) {
            const int* ngp = ng + (size_t)(bp0 + p_i) * Cc * Ss + aa;
            #pragma unroll
            for (int cc = 0; cc < Cc; ++cc) any |= ngp[cc * Ss];
        }
        maskneg[p_i][aa] = any ? 0.0f : NEGV;
    }
    __syncthreads();

    if (tid < 64) {    // wave 0: sumW[c]
        float s = 0.f;
        #pragma unroll
        for (int i = 0; i < Hh / 64; ++i) s += wc_s[tid + i * 64];
        #pragma unroll
        for (int off = 32; off; off >>= 1) s += __shfl_xor(s, off, 64);
        if (tid == 0) swr_s = s;
    }

    // thread's ha stream: float4 index = hg*128 + a, hg in [hh*96, hh*96+96)
    const float4* hap4 = (const float4*)(haT + (size_t)b * HA_B + (size_t)c * HA_C)
                       + (size_t)hh * 96 * 128 + a;
    const int hbase = hh * 384;

    float4 A0, A1, A2, A3, A4, A5, A6, A7;
    float4 B0, B1, B2, B3, B4, B5, B6, B7;
    float ac00 = 0.f, ac01 = 0.f, ac10 = 0.f, ac11 = 0.f;

    LOADG(A, 0)  SB
    LOADG(B, 1)  SB  CONSUMEG(A, 0)  SB
    LOADG(A, 2)  SB  CONSUMEG(B, 1)  SB
    LOADG(B, 3)  SB  CONSUMEG(A, 2)  SB
    LOADG(A, 4)  SB  CONSUMEG(B, 3)  SB
    LOADG(B, 5)  SB  CONSUMEG(A, 4)  SB
    LOADG(A, 6)  SB  CONSUMEG(B, 5)  SB
    LOADG(B, 7)  SB  CONSUMEG(A, 6)  SB
    LOADG(A, 8)  SB  CONSUMEG(B, 7)  SB
    LOADG(B, 9)  SB  CONSUMEG(A, 8)  SB
    LOADG(A, 10) SB  CONSUMEG(B, 9)  SB
    LOADG(B, 11) SB  CONSUMEG(A, 10) SB
    CONSUMEG(B, 11)

    if (hh == 1) {
        partial[0][a] = ac00 + ac01;
        partial[1][a] = ac10 + ac11;
    }
    __syncthreads();

    float logit[PT];
    const int wv = tid >> 6;             // 0/1 for hh==0 threads
    if (hh == 0) {
        const float ps[PT] = { ac00 + ac01, ac10 + ac11 };
        #pragma unroll
        for (int p = 0; p < PT; ++p) {
            logit[p] = swr_s - 2.0f * (ps[p] + partial[p][a]) + maskneg[p][a];
            out_logits[((size_t)(bp0 + p) * Cc + c) * Ss + a] = logit[p];
            float mx = logit[p];
            #pragma unroll
            for (int off = 32; off; off >>= 1) mx = fmaxf(mx, __shfl_xor(mx, off, 64));
            if (lane == 0) redmax[p][wv] = mx;
        }
    }
    __syncthreads();

    if (hh == 0) {
        #pragma unroll
        for (int p = 0; p < PT; ++p) {
            const float rm = fmaxf(redmax[p][0], redmax[p][1]);
            const float e  = __builtin_amdgcn_exp2f((logit[p] - rm) * 1.4426950408889634f);
            const float tg = target[((size_t)(bp0 + p) * Cc + c) * Ss + a];
            float se = e, st = tg, sx = tg * logit[p];
            #pragma unroll
            for (int off = 32; off; off >>= 1) {
                se += __shfl_xor(se, off, 64);
                st += __shfl_xor(st, off, 64);
                sx += __shfl_xor(sx, off, 64);
            }
            if (lane == 0) { red3[p][wv][0] = se; red3[p][wv][1] = st; red3[p][wv][2] = sx; }
        }
    }
    __syncthreads();

    if (tid == 0) {
        float nsum = 0.f, dsum = 0.f;
        #pragma unroll
        for (int p = 0; p < PT; ++p) {
            const float rm = fmaxf(redmax[p][0], redmax[p][1]);
            const float SE = red3[p][0][0] + red3[p][1][0];
            const float ST = red3[p][0][1] + red3[p][1][1];
            const float SX = red3[p][0][2] + red3[p][1][2];
            const float lse = rm + __builtin_amdgcn_logf(SE) * 0.6931471805599453f;
            nsum += lse * ST - SX;
            dsum += ST;
        }
        atomicAdd(&accum[0], nsum);
        atomicAdd(&accum[1], dsum);
        __threadfence();
        const unsigned old = atomicAdd((unsigned*)(accum + 2), 1u);
        if (old == (unsigned)(NBLK - 1)) {          // last block: finalize loss
            const float n = atomicAdd(&accum[0], 0.0f);
            const float d = atomicAdd(&accum[1], 0.0f);
            out_loss[0] = n / d;
        }
    }
}

extern "C" void kernel_launch(void* const* d_in, const int* in_sizes, int n_in,
                              void* d_out, int out_size, void* d_ws, size_t ws_size,
                              hipStream_t stream) {
    const float* seq    = (const float*)d_in[0];
    const int*   att    = (const int*)  d_in[1];
    const int*   ng     = (const int*)  d_in[2];
    const float* target = (const float*)d_in[3];
    const float* Wprd   = (const float*)d_in[4];
    const float* bprd   = (const float*)d_in[5];
    const float* Warg   = (const float*)d_in[6];
    const float* barg   = (const float*)d_in[7];
    const float* Wout   = (const float*)d_in[8];

    float* out    = (float*)d_out;
    float* hp_out = (float*)d_ws;                        // 256*768 floats
    float* haT    = hp_out + (size_t)Mm * Hh;            // 2*491520 floats
    float* accum  = haT + 2 * (size_t)HA_B;              // 3 slots

    gemm_mfma<<<dim3(4, 144), 256, 0, stream>>>(seq, Wprd, Warg, bprd, barg,
                                                hp_out, haT, accum);
    biaffine_loss<<<dim3(NBLK), 256, 0, stream>>>(hp_out, haT, Wout, ng, att, target,
                                                  out + 1, accum, out);
}